// Round 3
// baseline (176.145 us; speedup 1.0000x reference)
//
#include <hip/hip_runtime.h>
#include <hip/hip_cooperative_groups.h>
#include <math.h>

namespace cg = cooperative_groups;

#define BB 8
#define SS 512
#define HH 768
#define H4 (HH/4)
#define NTOT (BB*SS*HH)
#define N4 (NTOT/4)
#define EPSBN 1e-5f
#define GRID 512
#define TPB 256

typedef __attribute__((ext_vector_type(8))) short short8v;   // 8 bf16
typedef __attribute__((ext_vector_type(4))) float float4v;

struct Params {
  const float *x, *u, *ap;
  const float *w_nor3, *g_nor3, *b_nor3;
  const float *w_nor5, *g_nor5, *b_nor5;
  const float *w_nor7, *g_nor7, *b_nor7;
  const float *wd3, *wp3, *gd3, *bd3;
  const float *wd5, *wp5, *gd5, *bd5;
  const float *wd7, *wp7, *gd7, *bd7;
  float *out;
  float *y;      // [B][S][H] branch pre-BN output
  float *z;      // [B][S][H] depthwise intermediate
  float *psum;   // [16][H]
  float *psq;    // [16][H]
  float *mbuf;   // [H]
  float *ibuf;   // [H]
};

__device__ __forceinline__ short f2bf(float f) {
  union { float f; unsigned u; } v; v.f = f;
  unsigned r = v.u + 0x7FFF + ((v.u >> 16) & 1);   // RNE
  return (short)(r >> 16);
}

// Single cooperative kernel: gate + all 10 branches + BN + epilogue.
// grid=512 (2 blocks/CU, co-resident), block=256. Simple branches take the
// zero-sync fast path; conv branches use grid.sync() between phases.
__global__ __launch_bounds__(TPB, 2) void nas_coop(Params p) {
  cg::grid_group gg = cg::this_grid();
  int t = threadIdx.x;
  int bid = blockIdx.x;

  // ---- Gumbel straight-through gate (uniform across all threads) ----
  float apv[10], lg[10], pr[10];
  float mx = -INFINITY;
#pragma unroll
  for (int i = 0; i < 10; i++) { apv[i] = p.ap[i]; mx = fmaxf(mx, apv[i]); }
  float se = 0.f;
#pragma unroll
  for (int i = 0; i < 10; i++) se += expf(apv[i] - mx);
  float lse = mx + logf(se);
  float lmax = -INFINITY;
#pragma unroll
  for (int i = 0; i < 10; i++) {
    float uc = fminf(fmaxf(p.u[i], 1e-9f), 1.f - 1e-9f);
    float gb = -logf(-logf(uc));
    lg[i] = ((apv[i] - lse) + gb) * 0.1f;   // / TEM=10
    lmax = fmaxf(lmax, lg[i]);
  }
  float ps = 0.f;
#pragma unroll
  for (int i = 0; i < 10; i++) { pr[i] = expf(lg[i] - lmax); ps += pr[i]; }
  int idx = 0; float best = -INFINITY;
#pragma unroll
  for (int i = 0; i < 10; i++) {
    pr[i] /= ps;
    if (pr[i] > best) { best = pr[i]; idx = i; }
  }
  // hardwts[j!=idx] = (0-p)+p = 0 exactly; sum(w)-w_sel = 0 exactly
  float w_sel = (1.0f - pr[idx]) + pr[idx];

  const float4* x4 = (const float4*)p.x;
  float4* o4 = (float4*)p.out;

  // ================= simple branches: none/avg/max/skip =================
  if (idx < 3 || idx > 8) {
    for (int i = bid * TPB + t; i < N4; i += GRID * TPB) {
      float4 xv = x4[i];
      float4 sel;
      if (idx == 0) {
        sel = make_float4(0.f, 0.f, 0.f, 0.f);
      } else if (idx == 9) {
        sel = xv;
      } else {
        int row = i / H4;
        int s = row % SS;
        if (idx == 1) {  // avg_pool3, count_include_pad
          float4 xm = (s > 0) ? x4[i - H4] : make_float4(0.f, 0.f, 0.f, 0.f);
          float4 xp = (s < SS - 1) ? x4[i + H4] : make_float4(0.f, 0.f, 0.f, 0.f);
          sel.x = (xm.x + xv.x + xp.x) * (1.f / 3.f);
          sel.y = (xm.y + xv.y + xp.y) * (1.f / 3.f);
          sel.z = (xm.z + xv.z + xp.z) * (1.f / 3.f);
          sel.w = (xm.w + xv.w + xp.w) * (1.f / 3.f);
        } else {         // max_pool3, -inf pad
          float4 xm = (s > 0) ? x4[i - H4] : make_float4(-INFINITY, -INFINITY, -INFINITY, -INFINITY);
          float4 xp = (s < SS - 1) ? x4[i + H4] : make_float4(-INFINITY, -INFINITY, -INFINITY, -INFINITY);
          sel.x = fmaxf(fmaxf(xm.x, xv.x), xp.x);
          sel.y = fmaxf(fmaxf(xm.y, xv.y), xp.y);
          sel.z = fmaxf(fmaxf(xm.z, xv.z), xp.z);
          sel.w = fmaxf(fmaxf(xm.w, xv.w), xp.w);
        }
      }
      float4 ov;
      ov.x = w_sel * sel.x + xv.x;
      ov.y = w_sel * sel.y + xv.y;
      ov.z = w_sel * sel.z + xv.z;
      ov.w = w_sel * sel.w + xv.w;
      o4[i] = ov;
    }
    return;   // uniform: every thread in the grid returns, no syncs used
  }

  // ================= conv branches =================
  bool nor = (idx <= 5);
  int k = nor ? (3 + 2 * (idx - 3)) : (3 + 2 * (idx - 6));

  __shared__ __attribute__((aligned(16))) short lds[2 * 64 * 40];
  short* As = lds;
  short* Bs = lds + 64 * 40;

  // ---- depthwise dilated conv (dil only) ----
  if (!nor) {
    const float* wd = (idx == 6) ? p.wd3 : (idx == 7) ? p.wd5 : p.wd7;
    float4* z4 = (float4*)p.z;
    for (int i = bid * TPB + t; i < N4; i += GRID * TPB) {
      int row = i / H4;
      int c0 = (i - row * H4) * 4;
      int s = row % SS;
      int b = row / SS;
      float4 acc = make_float4(0.f, 0.f, 0.f, 0.f);
      for (int dk = 0; dk < k; dk++) {
        int ss = s + 2 * dk - (k - 1);
        if (ss >= 0 && ss < SS) {
          float4 xv = x4[(b * SS + ss) * H4 + (c0 >> 2)];
          acc.x += fmaxf(xv.x, 0.f) * wd[(c0 + 0) * k + dk];
          acc.y += fmaxf(xv.y, 0.f) * wd[(c0 + 1) * k + dk];
          acc.z += fmaxf(xv.z, 0.f) * wd[(c0 + 2) * k + dk];
          acc.w += fmaxf(xv.w, 0.f) * wd[(c0 + 3) * k + dk];
        }
      }
      z4[i] = acc;
    }
    gg.sync();
  }

  // ---- bf16 MFMA GEMM: y[b,s,o], tiles 64x64, BK=32 ----
  const float* W = nor ? ((idx == 3) ? p.w_nor3 : (idx == 4) ? p.w_nor5 : p.w_nor7)
                       : ((idx == 6) ? p.wp3 : (idx == 7) ? p.wp5 : p.wp7);
  const float* A = nor ? p.x : p.z;
  int taps = nor ? k : 1;
  int halo = nor ? (k >> 1) : 0;

  int lane = t & 63, wid = t >> 6;
  int wm0 = (wid >> 1) * 32, wn0 = (wid & 1) * 32;
  int l16 = lane & 15, quad = lane >> 4;
  int s_row = t >> 2, s_seg = t & 3;

  for (int tile = bid; tile < 64 * 12; tile += GRID) {
    int mt = tile & 63, nt = tile >> 6;
    int b = mt >> 3, s0 = (mt & 7) * 64, o0 = nt * 64;
    float4v acc[2][2];
#pragma unroll
    for (int mi = 0; mi < 2; mi++)
#pragma unroll
      for (int ni = 0; ni < 2; ni++) acc[mi][ni] = (float4v){0.f, 0.f, 0.f, 0.f};

    for (int dk = 0; dk < taps; dk++) {
      int shift = dk - halo;
      for (int k0 = 0; k0 < HH; k0 += 32) {
        // stage A: 64 rows x 32 ch, relu for nor
        {
          int srow = s0 + s_row + shift;
          float4 f0, f1;
          if (srow >= 0 && srow < SS) {
            const float* apt = A + ((size_t)(b * SS + srow)) * HH + k0 + s_seg * 8;
            f0 = ((const float4*)apt)[0];
            f1 = ((const float4*)apt)[1];
          } else {
            f0 = make_float4(0.f, 0.f, 0.f, 0.f);
            f1 = f0;
          }
          if (nor) {
            f0.x = fmaxf(f0.x, 0.f); f0.y = fmaxf(f0.y, 0.f); f0.z = fmaxf(f0.z, 0.f); f0.w = fmaxf(f0.w, 0.f);
            f1.x = fmaxf(f1.x, 0.f); f1.y = fmaxf(f1.y, 0.f); f1.z = fmaxf(f1.z, 0.f); f1.w = fmaxf(f1.w, 0.f);
          }
          short h8[8];
          h8[0] = f2bf(f0.x); h8[1] = f2bf(f0.y); h8[2] = f2bf(f0.z); h8[3] = f2bf(f0.w);
          h8[4] = f2bf(f1.x); h8[5] = f2bf(f1.y); h8[6] = f2bf(f1.z); h8[7] = f2bf(f1.w);
          *(short8v*)&As[s_row * 40 + s_seg * 8] = *(short8v*)&h8[0];
        }
        // stage B: 64 outs x 32 ch
        {
          int o = o0 + s_row;
          short hb[8];
          if (!nor) {
            const float* bp = W + (size_t)o * HH + k0 + s_seg * 8;
            float4 g0 = ((const float4*)bp)[0];
            float4 g1 = ((const float4*)bp)[1];
            hb[0] = f2bf(g0.x); hb[1] = f2bf(g0.y); hb[2] = f2bf(g0.z); hb[3] = f2bf(g0.w);
            hb[4] = f2bf(g1.x); hb[5] = f2bf(g1.y); hb[6] = f2bf(g1.z); hb[7] = f2bf(g1.w);
          } else {
#pragma unroll
            for (int j = 0; j < 8; j++)
              hb[j] = f2bf(W[((size_t)o * HH + k0 + s_seg * 8 + j) * k + dk]);
          }
          *(short8v*)&Bs[s_row * 40 + s_seg * 8] = *(short8v*)&hb[0];
        }
        __syncthreads();
        short8v af[2], bf[2];
#pragma unroll
        for (int mi = 0; mi < 2; mi++)
          af[mi] = *(const short8v*)&As[(wm0 + mi * 16 + l16) * 40 + quad * 8];
#pragma unroll
        for (int ni = 0; ni < 2; ni++)
          bf[ni] = *(const short8v*)&Bs[(wn0 + ni * 16 + l16) * 40 + quad * 8];
#pragma unroll
        for (int mi = 0; mi < 2; mi++)
#pragma unroll
          for (int ni = 0; ni < 2; ni++)
            acc[mi][ni] = __builtin_amdgcn_mfma_f32_16x16x32_bf16(af[mi], bf[ni], acc[mi][ni], 0, 0, 0);
        __syncthreads();
      }
    }
    // C/D layout: col=lane&15, row=quad*4+reg
#pragma unroll
    for (int mi = 0; mi < 2; mi++)
#pragma unroll
      for (int ni = 0; ni < 2; ni++) {
        int col = o0 + wn0 + ni * 16 + l16;
#pragma unroll
        for (int r = 0; r < 4; r++) {
          int row = s0 + wm0 + mi * 16 + quad * 4 + r;
          p.y[((size_t)(b * SS + row)) * HH + col] = acc[mi][ni][r];
        }
      }
  }
  gg.sync();

  // ---- BN stats stage 1: 192 logical blocks ----
  if (bid < 192) {
    int rchunk = bid & 15, cgp = bid >> 4;
    int c = cgp * 64 + (t & 63);
    int rsub = t >> 6;
    float s_ = 0.f, q = 0.f;
    int rbase = rchunk * 256 + rsub;
    for (int j = 0; j < 64; j++) {
      float v = p.y[(size_t)(rbase + 4 * j) * HH + c];
      s_ += v; q += v * v;
    }
    float* red = (float*)lds;   // 2*4*64 floats = 2 KB
    red[(0 * 4 + rsub) * 64 + (t & 63)] = s_;
    red[(1 * 4 + rsub) * 64 + (t & 63)] = q;
    __syncthreads();
    if (t < 64) {
      float ts = red[t] + red[64 + t] + red[128 + t] + red[192 + t];
      float tq = red[256 + t] + red[320 + t] + red[384 + t] + red[448 + t];
      p.psum[rchunk * HH + cgp * 64 + t] = ts;
      p.psq[rchunk * HH + cgp * 64 + t] = tq;
    }
  }
  gg.sync();

  // ---- BN stats stage 2: 3 logical blocks ----
  if (bid < 3) {
    int c = bid * TPB + t;
    float s_ = 0.f, q = 0.f;
    for (int j = 0; j < 16; j++) { s_ += p.psum[j * HH + c]; q += p.psq[j * HH + c]; }
    float mean = s_ * (1.f / 4096.f);
    float var = q * (1.f / 4096.f) - mean * mean;
    p.mbuf[c] = mean;
    p.ibuf[c] = rsqrtf(var + EPSBN);
  }
  gg.sync();

  // ---- conv epilogue: BN apply + gate + residual ----
  {
    const float* g = (idx == 3) ? p.g_nor3 : (idx == 4) ? p.g_nor5 : (idx == 5) ? p.g_nor7
                   : (idx == 6) ? p.gd3 : (idx == 7) ? p.gd5 : p.gd7;
    const float* be = (idx == 3) ? p.b_nor3 : (idx == 4) ? p.b_nor5 : (idx == 5) ? p.b_nor7
                    : (idx == 6) ? p.bd3 : (idx == 7) ? p.bd5 : p.bd7;
    const float4* y4 = (const float4*)p.y;
    for (int i = bid * TPB + t; i < N4; i += GRID * TPB) {
      int c0 = (i % H4) * 4;
      float4 xv = x4[i], yv = y4[i];
      float4 sel, ov;
      sel.x = (yv.x - p.mbuf[c0 + 0]) * p.ibuf[c0 + 0] * g[c0 + 0] + be[c0 + 0];
      sel.y = (yv.y - p.mbuf[c0 + 1]) * p.ibuf[c0 + 1] * g[c0 + 1] + be[c0 + 1];
      sel.z = (yv.z - p.mbuf[c0 + 2]) * p.ibuf[c0 + 2] * g[c0 + 2] + be[c0 + 2];
      sel.w = (yv.w - p.mbuf[c0 + 3]) * p.ibuf[c0 + 3] * g[c0 + 3] + be[c0 + 3];
      ov.x = w_sel * sel.x + xv.x;
      ov.y = w_sel * sel.y + xv.y;
      ov.z = w_sel * sel.z + xv.z;
      ov.w = w_sel * sel.w + xv.w;
      o4[i] = ov;
    }
  }
}

extern "C" void kernel_launch(void* const* d_in, const int* in_sizes, int n_in,
                              void* d_out, int out_size, void* d_ws, size_t ws_size,
                              hipStream_t stream) {
  Params p;
  p.x = (const float*)d_in[0];
  p.u = (const float*)d_in[1];
  p.ap = (const float*)d_in[2];
  p.w_nor3 = (const float*)d_in[3];  p.g_nor3 = (const float*)d_in[4];  p.b_nor3 = (const float*)d_in[5];
  p.w_nor5 = (const float*)d_in[6];  p.g_nor5 = (const float*)d_in[7];  p.b_nor5 = (const float*)d_in[8];
  p.w_nor7 = (const float*)d_in[9];  p.g_nor7 = (const float*)d_in[10]; p.b_nor7 = (const float*)d_in[11];
  p.wd3 = (const float*)d_in[12]; p.wp3 = (const float*)d_in[13]; p.gd3 = (const float*)d_in[14]; p.bd3 = (const float*)d_in[15];
  p.wd5 = (const float*)d_in[16]; p.wp5 = (const float*)d_in[17]; p.gd5 = (const float*)d_in[18]; p.bd5 = (const float*)d_in[19];
  p.wd7 = (const float*)d_in[20]; p.wp7 = (const float*)d_in[21]; p.gd7 = (const float*)d_in[22]; p.bd7 = (const float*)d_in[23];
  p.out = (float*)d_out;

  char* ws = (char*)d_ws;
  size_t off = 0;
  p.y   = (float*)(ws + off); off += (size_t)NTOT * 4;
  p.z   = (float*)(ws + off); off += (size_t)NTOT * 4;
  p.psum = (float*)(ws + off); off += 16 * HH * 4;
  p.psq  = (float*)(ws + off); off += 16 * HH * 4;
  p.mbuf = (float*)(ws + off); off += HH * 4;
  p.ibuf = (float*)(ws + off); off += HH * 4;

  Params* pp = &p;
  void* args[] = { (void*)pp };
  hipLaunchCooperativeKernel((const void*)nas_coop, dim3(GRID), dim3(TPB),
                             args, 0, stream);
}

// Round 4
// 146.854 us; speedup vs baseline: 1.1995x; 1.1995x over previous
//
#include <hip/hip_runtime.h>
#include <math.h>

#define BB 8
#define SS 512
#define HH 768
#define H4 (HH/4)
#define NTOT (BB*SS*HH)
#define N4 (NTOT/4)
#define EPSBN 1e-5f
#define GSB 1024   // grid-stride blocks for elementwise passes
#define TPB 256

typedef __attribute__((ext_vector_type(8))) short short8v;   // 8 bf16
typedef __attribute__((ext_vector_type(4))) float float4v;

struct Params {
  const float *x, *u, *ap;
  const float *w_nor3, *g_nor3, *b_nor3;
  const float *w_nor5, *g_nor5, *b_nor5;
  const float *w_nor7, *g_nor7, *b_nor7;
  const float *wd3, *wp3, *gd3, *bd3;
  const float *wd5, *wp5, *gd5, *bd5;
  const float *wd7, *wp7, *gd7, *bd7;
  float *out;
  float *y;      // [B][S][H] branch pre-BN output
  float *z;      // [B][S][H] depthwise intermediate
  float *psum;   // [16][H]
  float *psq;    // [16][H]
};

__device__ __forceinline__ short f2bf(float f) {
  union { float f; unsigned u; } v; v.f = f;
  unsigned r = v.u + 0x7FFF + ((v.u >> 16) & 1);   // RNE
  return (short)(r >> 16);
}

// Gumbel straight-through gate — uniform, deterministic, computed inline
// by every thread of every kernel (~40 transcendentals, negligible).
__device__ __forceinline__ void gate(const float* ap_, const float* u_,
                                     int& idx, float& w_sel) {
  float apv[10], lg[10], pr[10];
  float mx = -INFINITY;
#pragma unroll
  for (int i = 0; i < 10; i++) { apv[i] = ap_[i]; mx = fmaxf(mx, apv[i]); }
  float se = 0.f;
#pragma unroll
  for (int i = 0; i < 10; i++) se += expf(apv[i] - mx);
  float lse = mx + logf(se);
  float lmax = -INFINITY;
#pragma unroll
  for (int i = 0; i < 10; i++) {
    float uc = fminf(fmaxf(u_[i], 1e-9f), 1.f - 1e-9f);
    float gb = -logf(-logf(uc));
    lg[i] = ((apv[i] - lse) + gb) * 0.1f;   // / TEM=10
    lmax = fmaxf(lmax, lg[i]);
  }
  float ps = 0.f;
#pragma unroll
  for (int i = 0; i < 10; i++) { pr[i] = expf(lg[i] - lmax); ps += pr[i]; }
  idx = 0; float best = -INFINITY;
#pragma unroll
  for (int i = 0; i < 10; i++) {
    pr[i] /= ps;
    if (pr[i] > best) { best = pr[i]; idx = i; }
  }
  // hardwts[j!=idx] = (0-p)+p = 0 exactly; sum(w) - w_sel = 0 exactly
  w_sel = (1.0f - pr[idx]) + pr[idx];
}

// ---- K1: simple branches -> final out; dil -> depthwise z; nor -> exit ----
__global__ __launch_bounds__(TPB) void k_pre(Params p) {
  int idx; float w_sel;
  gate(p.ap, p.u, idx, w_sel);
  int t0 = blockIdx.x * TPB + threadIdx.x;
  const float4* x4 = (const float4*)p.x;

  if (idx >= 3 && idx <= 5) return;   // nor_conv: nothing to do here

  if (idx >= 6 && idx <= 8) {         // dil: depthwise dilated conv -> z
    int k = 3 + 2 * (idx - 6);
    const float* wd = (idx == 6) ? p.wd3 : (idx == 7) ? p.wd5 : p.wd7;
    float4* z4 = (float4*)p.z;
    for (int i = t0; i < N4; i += GSB * TPB) {
      int row = i / H4;
      int c0 = (i - row * H4) * 4;
      int s = row % SS;
      int b = row / SS;
      float4 acc = make_float4(0.f, 0.f, 0.f, 0.f);
      for (int dk = 0; dk < k; dk++) {
        int ss = s + 2 * dk - (k - 1);
        if (ss >= 0 && ss < SS) {
          float4 xv = x4[(b * SS + ss) * H4 + (c0 >> 2)];
          acc.x += fmaxf(xv.x, 0.f) * wd[(c0 + 0) * k + dk];
          acc.y += fmaxf(xv.y, 0.f) * wd[(c0 + 1) * k + dk];
          acc.z += fmaxf(xv.z, 0.f) * wd[(c0 + 2) * k + dk];
          acc.w += fmaxf(xv.w, 0.f) * wd[(c0 + 3) * k + dk];
        }
      }
      z4[i] = acc;
    }
    return;
  }

  // simple branches: none / avg_pool / max_pool / skip -> final output
  float4* o4 = (float4*)p.out;
  for (int i = t0; i < N4; i += GSB * TPB) {
    float4 xv = x4[i];
    float4 sel;
    if (idx == 0) {
      sel = make_float4(0.f, 0.f, 0.f, 0.f);
    } else if (idx == 9) {
      sel = xv;
    } else {
      int row = i / H4;
      int s = row % SS;
      if (idx == 1) {  // avg_pool3, count_include_pad
        float4 xm = (s > 0) ? x4[i - H4] : make_float4(0.f, 0.f, 0.f, 0.f);
        float4 xp = (s < SS - 1) ? x4[i + H4] : make_float4(0.f, 0.f, 0.f, 0.f);
        sel.x = (xm.x + xv.x + xp.x) * (1.f / 3.f);
        sel.y = (xm.y + xv.y + xp.y) * (1.f / 3.f);
        sel.z = (xm.z + xv.z + xp.z) * (1.f / 3.f);
        sel.w = (xm.w + xv.w + xp.w) * (1.f / 3.f);
      } else {         // max_pool3, -inf pad
        float4 xm = (s > 0) ? x4[i - H4] : make_float4(-INFINITY, -INFINITY, -INFINITY, -INFINITY);
        float4 xp = (s < SS - 1) ? x4[i + H4] : make_float4(-INFINITY, -INFINITY, -INFINITY, -INFINITY);
        sel.x = fmaxf(fmaxf(xm.x, xv.x), xp.x);
        sel.y = fmaxf(fmaxf(xm.y, xv.y), xp.y);
        sel.z = fmaxf(fmaxf(xm.z, xv.z), xp.z);
        sel.w = fmaxf(fmaxf(xm.w, xv.w), xp.w);
      }
    }
    float4 ov;
    ov.x = w_sel * sel.x + xv.x;
    ov.y = w_sel * sel.y + xv.y;
    ov.z = w_sel * sel.z + xv.z;
    ov.w = w_sel * sel.w + xv.w;
    o4[i] = ov;
  }
}

// ---- K2: conv branches bf16 MFMA GEMM -> y (64x64 tiles, BK=32) ----
__global__ __launch_bounds__(TPB) void k_gemm(Params p) {
  int idx; float w_sel;
  gate(p.ap, p.u, idx, w_sel);
  if (idx < 3 || idx > 8) return;
  bool nor = (idx <= 5);
  int k = nor ? (3 + 2 * (idx - 3)) : (3 + 2 * (idx - 6));
  const float* W = nor ? ((idx == 3) ? p.w_nor3 : (idx == 4) ? p.w_nor5 : p.w_nor7)
                       : ((idx == 6) ? p.wp3 : (idx == 7) ? p.wp5 : p.wp7);
  const float* A = nor ? p.x : p.z;
  int taps = nor ? k : 1;
  int halo = nor ? (k >> 1) : 0;

  __shared__ __attribute__((aligned(16))) short As[64 * 40];
  __shared__ __attribute__((aligned(16))) short Bs[64 * 40];

  int b = blockIdx.x >> 3;
  int s0 = (blockIdx.x & 7) * 64;
  int o0 = blockIdx.y * 64;

  int t = threadIdx.x;
  int lane = t & 63, wid = t >> 6;
  int wm0 = (wid >> 1) * 32, wn0 = (wid & 1) * 32;
  int l16 = lane & 15, quad = lane >> 4;
  int s_row = t >> 2, s_seg = t & 3;

  float4v acc[2][2];
#pragma unroll
  for (int mi = 0; mi < 2; mi++)
#pragma unroll
    for (int ni = 0; ni < 2; ni++) acc[mi][ni] = (float4v){0.f, 0.f, 0.f, 0.f};

  for (int dk = 0; dk < taps; dk++) {
    int shift = dk - halo;
    for (int k0 = 0; k0 < HH; k0 += 32) {
      {
        int srow = s0 + s_row + shift;
        float4 f0, f1;
        if (srow >= 0 && srow < SS) {
          const float* apt = A + ((size_t)(b * SS + srow)) * HH + k0 + s_seg * 8;
          f0 = ((const float4*)apt)[0];
          f1 = ((const float4*)apt)[1];
        } else {
          f0 = make_float4(0.f, 0.f, 0.f, 0.f);
          f1 = f0;
        }
        if (nor) {
          f0.x = fmaxf(f0.x, 0.f); f0.y = fmaxf(f0.y, 0.f); f0.z = fmaxf(f0.z, 0.f); f0.w = fmaxf(f0.w, 0.f);
          f1.x = fmaxf(f1.x, 0.f); f1.y = fmaxf(f1.y, 0.f); f1.z = fmaxf(f1.z, 0.f); f1.w = fmaxf(f1.w, 0.f);
        }
        short h8[8];
        h8[0] = f2bf(f0.x); h8[1] = f2bf(f0.y); h8[2] = f2bf(f0.z); h8[3] = f2bf(f0.w);
        h8[4] = f2bf(f1.x); h8[5] = f2bf(f1.y); h8[6] = f2bf(f1.z); h8[7] = f2bf(f1.w);
        *(short8v*)&As[s_row * 40 + s_seg * 8] = *(short8v*)&h8[0];
      }
      {
        int o = o0 + s_row;
        short hb[8];
        if (!nor) {
          const float* bp = W + (size_t)o * HH + k0 + s_seg * 8;
          float4 g0 = ((const float4*)bp)[0];
          float4 g1 = ((const float4*)bp)[1];
          hb[0] = f2bf(g0.x); hb[1] = f2bf(g0.y); hb[2] = f2bf(g0.z); hb[3] = f2bf(g0.w);
          hb[4] = f2bf(g1.x); hb[5] = f2bf(g1.y); hb[6] = f2bf(g1.z); hb[7] = f2bf(g1.w);
        } else {
#pragma unroll
          for (int j = 0; j < 8; j++)
            hb[j] = f2bf(W[((size_t)o * HH + k0 + s_seg * 8 + j) * k + dk]);
        }
        *(short8v*)&Bs[s_row * 40 + s_seg * 8] = *(short8v*)&hb[0];
      }
      __syncthreads();
      short8v af[2], bf[2];
#pragma unroll
      for (int mi = 0; mi < 2; mi++)
        af[mi] = *(const short8v*)&As[(wm0 + mi * 16 + l16) * 40 + quad * 8];
#pragma unroll
      for (int ni = 0; ni < 2; ni++)
        bf[ni] = *(const short8v*)&Bs[(wn0 + ni * 16 + l16) * 40 + quad * 8];
#pragma unroll
      for (int mi = 0; mi < 2; mi++)
#pragma unroll
        for (int ni = 0; ni < 2; ni++)
          acc[mi][ni] = __builtin_amdgcn_mfma_f32_16x16x32_bf16(af[mi], bf[ni], acc[mi][ni], 0, 0, 0);
      __syncthreads();
    }
  }
  // C/D layout: col=lane&15, row=quad*4+reg
#pragma unroll
  for (int mi = 0; mi < 2; mi++)
#pragma unroll
    for (int ni = 0; ni < 2; ni++) {
      int col = o0 + wn0 + ni * 16 + l16;
#pragma unroll
      for (int r = 0; r < 4; r++) {
        int row = s0 + wm0 + mi * 16 + quad * 4 + r;
        p.y[((size_t)(b * SS + row)) * HH + col] = acc[mi][ni][r];
      }
    }
}

// ---- K3: BN partial sums over 256-row chunks (conv only) ----
__global__ __launch_bounds__(TPB) void k_bn1(Params p) {
  int idx; float w_sel;
  gate(p.ap, p.u, idx, w_sel);
  if (idx < 3 || idx > 8) return;
  int t = threadIdx.x;
  int c = blockIdx.y * 64 + (t & 63);
  int rsub = t >> 6;
  float s = 0.f, q = 0.f;
  int rbase = blockIdx.x * 256 + rsub;
  for (int j = 0; j < 64; j++) {
    float v = p.y[(size_t)(rbase + 4 * j) * HH + c];
    s += v; q += v * v;
  }
  __shared__ float red[2][4][64];
  red[0][rsub][t & 63] = s;
  red[1][rsub][t & 63] = q;
  __syncthreads();
  if (t < 64) {
    float ts = red[0][0][t] + red[0][1][t] + red[0][2][t] + red[0][3][t];
    float tq = red[1][0][t] + red[1][1][t] + red[1][2][t] + red[1][3][t];
    p.psum[blockIdx.x * HH + blockIdx.y * 64 + t] = ts;
    p.psq[blockIdx.x * HH + blockIdx.y * 64 + t] = tq;
  }
}

// ---- K4: finalize stats per-block into LDS, then BN + gate + residual ----
__global__ __launch_bounds__(TPB) void k_post(Params p) {
  int idx; float w_sel;
  gate(p.ap, p.u, idx, w_sel);
  if (idx < 3 || idx > 8) return;
  const float* g = (idx == 3) ? p.g_nor3 : (idx == 4) ? p.g_nor5 : (idx == 5) ? p.g_nor7
                 : (idx == 6) ? p.gd3 : (idx == 7) ? p.gd5 : p.gd7;
  const float* be = (idx == 3) ? p.b_nor3 : (idx == 4) ? p.b_nor5 : (idx == 5) ? p.b_nor7
                  : (idx == 6) ? p.bd3 : (idx == 7) ? p.bd5 : p.bd7;

  __shared__ float ms[HH];   // mean
  __shared__ float iv[HH];   // rsqrt(var+eps) * gamma
  __shared__ float bb[HH];   // beta
  for (int c = threadIdx.x; c < HH; c += TPB) {
    float s = 0.f, q = 0.f;
#pragma unroll
    for (int j = 0; j < 16; j++) { s += p.psum[j * HH + c]; q += p.psq[j * HH + c]; }
    float mean = s * (1.f / 4096.f);
    float var = q * (1.f / 4096.f) - mean * mean;
    ms[c] = mean;
    iv[c] = rsqrtf(var + EPSBN) * g[c];
    bb[c] = be[c];
  }
  __syncthreads();

  const float4* x4 = (const float4*)p.x;
  const float4* y4 = (const float4*)p.y;
  float4* o4 = (float4*)p.out;
  for (int i = blockIdx.x * TPB + threadIdx.x; i < N4; i += GSB * TPB) {
    int c0 = (i % H4) * 4;
    float4 xv = x4[i], yv = y4[i];
    float4 ov;
    ov.x = w_sel * ((yv.x - ms[c0 + 0]) * iv[c0 + 0] + bb[c0 + 0]) + xv.x;
    ov.y = w_sel * ((yv.y - ms[c0 + 1]) * iv[c0 + 1] + bb[c0 + 1]) + xv.y;
    ov.z = w_sel * ((yv.z - ms[c0 + 2]) * iv[c0 + 2] + bb[c0 + 2]) + xv.z;
    ov.w = w_sel * ((yv.w - ms[c0 + 3]) * iv[c0 + 3] + bb[c0 + 3]) + xv.w;
    o4[i] = ov;
  }
}

extern "C" void kernel_launch(void* const* d_in, const int* in_sizes, int n_in,
                              void* d_out, int out_size, void* d_ws, size_t ws_size,
                              hipStream_t stream) {
  Params p;
  p.x = (const float*)d_in[0];
  p.u = (const float*)d_in[1];
  p.ap = (const float*)d_in[2];
  p.w_nor3 = (const float*)d_in[3];  p.g_nor3 = (const float*)d_in[4];  p.b_nor3 = (const float*)d_in[5];
  p.w_nor5 = (const float*)d_in[6];  p.g_nor5 = (const float*)d_in[7];  p.b_nor5 = (const float*)d_in[8];
  p.w_nor7 = (const float*)d_in[9];  p.g_nor7 = (const float*)d_in[10]; p.b_nor7 = (const float*)d_in[11];
  p.wd3 = (const float*)d_in[12]; p.wp3 = (const float*)d_in[13]; p.gd3 = (const float*)d_in[14]; p.bd3 = (const float*)d_in[15];
  p.wd5 = (const float*)d_in[16]; p.wp5 = (const float*)d_in[17]; p.gd5 = (const float*)d_in[18]; p.bd5 = (const float*)d_in[19];
  p.wd7 = (const float*)d_in[20]; p.wp7 = (const float*)d_in[21]; p.gd7 = (const float*)d_in[22]; p.bd7 = (const float*)d_in[23];
  p.out = (float*)d_out;

  char* ws = (char*)d_ws;
  size_t off = 0;
  p.y   = (float*)(ws + off); off += (size_t)NTOT * 4;
  p.z   = (float*)(ws + off); off += (size_t)NTOT * 4;
  p.psum = (float*)(ws + off); off += 16 * HH * 4;
  p.psq  = (float*)(ws + off); off += 16 * HH * 4;

  hipLaunchKernelGGL(k_pre, dim3(GSB), dim3(TPB), 0, stream, p);
  hipLaunchKernelGGL(k_gemm, dim3(64, 12), dim3(TPB), 0, stream, p);
  hipLaunchKernelGGL(k_bn1, dim3(16, 12), dim3(TPB), 0, stream, p);
  hipLaunchKernelGGL(k_post, dim3(GSB), dim3(TPB), 0, stream, p);
}